// Round 1
// baseline (644.092 us; speedup 1.0000x reference)
//
#include <hip/hip_runtime.h>
#include <math.h>

#define BB 512
#define TT 256
#define CC 384
#define HH 64
// M = BB*TT = 131072 rows for the projection GEMM

// ---------------------------------------------------------------------------
// Kernel 1: QKV projection GEMM, fp32 vector ALU.
// out[m][h] = sum_c x[m][c] * W[c][h]   (W stored [C][H] row-major)
// Block: 256 threads (16x16). Tile: 128 rows x 64 cols (full H). K-chunk 32.
// blockIdx.y selects which of Wk/Wq/Wv -> kbuf/qbuf/vbuf.
// ---------------------------------------------------------------------------
__global__ __launch_bounds__(256) void qkv_gemm(
    const float* __restrict__ x,
    const float* __restrict__ W0,   // Wk
    const float* __restrict__ W1,   // Wq
    const float* __restrict__ W2,   // Wv
    float* __restrict__ kbuf,
    float* __restrict__ qbuf,
    float* __restrict__ vbuf)
{
    // stride 36 floats: 16B-aligned rows; in-wave ty spacing hits banks {0,4,8,12} -> conflict-free broadcast
    __shared__ float xs[128][36];
    __shared__ float wsh[32][64];

    const int tid = threadIdx.x;
    const int tx = tid & 15;
    const int ty = tid >> 4;
    const int row0 = blockIdx.x * 128;
    const int mat = blockIdx.y;

    const float* W = (mat == 0) ? W0 : (mat == 1) ? W1 : W2;
    float* out      = (mat == 0) ? kbuf : (mat == 1) ? qbuf : vbuf;

    float acc[8][4];
    #pragma unroll
    for (int i = 0; i < 8; ++i)
        #pragma unroll
        for (int j = 0; j < 4; ++j) acc[i][j] = 0.f;

    for (int k0 = 0; k0 < CC; k0 += 32) {
        // x tile: 128 rows x 32 cols = 1024 float4, 4 per thread
        #pragma unroll
        for (int it = 0; it < 4; ++it) {
            int idx = tid + it * 256;
            int r   = idx >> 3;
            int c4  = idx & 7;
            float4 vv = *reinterpret_cast<const float4*>(
                &x[(size_t)(row0 + r) * CC + k0 + c4 * 4]);
            *reinterpret_cast<float4*>(&xs[r][c4 * 4]) = vv;
        }
        // W tile: 32 rows x 64 cols = 512 float4, 2 per thread
        #pragma unroll
        for (int it = 0; it < 2; ++it) {
            int idx = tid + it * 256;
            int r   = idx >> 4;
            int h4  = idx & 15;
            float4 vv = *reinterpret_cast<const float4*>(
                &W[(size_t)(k0 + r) * HH + h4 * 4]);
            *reinterpret_cast<float4*>(&wsh[r][h4 * 4]) = vv;
        }
        __syncthreads();

        #pragma unroll
        for (int kk = 0; kk < 32; ++kk) {
            float4 bv = *reinterpret_cast<const float4*>(&wsh[kk][tx * 4]);
            #pragma unroll
            for (int i = 0; i < 8; ++i) {
                float a = xs[ty + i * 16][kk];
                acc[i][0] += a * bv.x;
                acc[i][1] += a * bv.y;
                acc[i][2] += a * bv.z;
                acc[i][3] += a * bv.w;
            }
        }
        __syncthreads();
    }

    #pragma unroll
    for (int i = 0; i < 8; ++i) {
        float4 vv = make_float4(acc[i][0], acc[i][1], acc[i][2], acc[i][3]);
        *reinterpret_cast<float4*>(
            &out[(size_t)(row0 + ty + i * 16) * HH + tx * 4]) = vv;
    }
}

// ---------------------------------------------------------------------------
// Kernel 2: causal attention, flash-style, fp32.
// Block = (qtile, batch): 64 query rows. 256 threads: 4 lanes per query,
// each lane owns 16 of the 64 head dims. K/V streamed through LDS in
// 64-key tiles; online softmax with 16-key sub-chunks.
// ---------------------------------------------------------------------------
__global__ __launch_bounds__(256) void attn(
    const float* __restrict__ qbuf,
    const float* __restrict__ kbuf,
    const float* __restrict__ vbuf,
    float* __restrict__ out)
{
    __shared__ float ks[64][64];
    __shared__ float vs[64][64];

    const int tid = threadIdx.x;
    const int hg  = tid & 3;         // head-dim group (16 dims each)
    const int ql  = tid >> 2;        // query within tile, 0..63
    const int qt  = blockIdx.x;      // query tile, 0..3
    const int b   = blockIdx.y;      // batch
    const int qrow = qt * 64 + ql;
    const int wave_qmax = ((tid >> 6) << 4) + 15;   // max ql in this wave
    const float scale = 0.05103103630798287f;       // 1/sqrt(384)

    const size_t base = (size_t)b * TT * HH;

    // q row slice -> registers
    float qv[16];
    #pragma unroll
    for (int j = 0; j < 4; ++j) {
        float4 vv = *reinterpret_cast<const float4*>(
            &qbuf[base + (size_t)qrow * HH + hg * 16 + j * 4]);
        qv[j*4+0] = vv.x; qv[j*4+1] = vv.y; qv[j*4+2] = vv.z; qv[j*4+3] = vv.w;
    }

    float m = -INFINITY, l = 0.f;
    float acc[16];
    #pragma unroll
    for (int i = 0; i < 16; ++i) acc[i] = 0.f;

    for (int kt = 0; kt <= qt; ++kt) {
        __syncthreads();
        // stage K,V tiles: 64x64 floats each = 1024 float4 each
        #pragma unroll
        for (int it = 0; it < 4; ++it) {
            int idx = tid + it * 256;
            int s   = idx >> 4;
            int h4  = idx & 15;
            *reinterpret_cast<float4*>(&ks[s][h4 * 4]) =
                *reinterpret_cast<const float4*>(
                    &kbuf[base + (size_t)(kt * 64 + s) * HH + h4 * 4]);
            *reinterpret_cast<float4*>(&vs[s][h4 * 4]) =
                *reinterpret_cast<const float4*>(
                    &vbuf[base + (size_t)(kt * 64 + s) * HH + h4 * 4]);
        }
        __syncthreads();

        const bool diag = (kt == qt);
        for (int sub = 0; sub < 4; ++sub) {
            int s0 = sub * 16;
            if (diag && s0 > wave_qmax) break;   // wave-uniform early-out

            float w[16];
            #pragma unroll
            for (int si = 0; si < 16; ++si) {
                int s = s0 + si;
                float p = 0.f;
                #pragma unroll
                for (int j = 0; j < 4; ++j) {
                    float4 kv = *reinterpret_cast<const float4*>(
                        &ks[s][hg * 16 + j * 4]);
                    p += qv[j*4+0]*kv.x + qv[j*4+1]*kv.y
                       + qv[j*4+2]*kv.z + qv[j*4+3]*kv.w;
                }
                // reduce partial dot across the 4 lanes of this query
                p += __shfl_xor(p, 1);
                p += __shfl_xor(p, 2);
                p *= scale;
                if (diag && (s > ql)) p = -INFINITY;
                w[si] = p;
            }

            float mx = w[0];
            #pragma unroll
            for (int si = 1; si < 16; ++si) mx = fmaxf(mx, w[si]);
            float nm   = fmaxf(m, mx);
            float corr = __expf(m - nm);   // m starts -inf, nm finite from first chunk

            float sum = 0.f;
            #pragma unroll
            for (int si = 0; si < 16; ++si) {
                w[si] = __expf(w[si] - nm);
                sum += w[si];
            }
            l = l * corr + sum;
            #pragma unroll
            for (int i = 0; i < 16; ++i) acc[i] *= corr;

            #pragma unroll
            for (int si = 0; si < 16; ++si) {
                #pragma unroll
                for (int j = 0; j < 4; ++j) {
                    float4 vv = *reinterpret_cast<const float4*>(
                        &vs[s0 + si][hg * 16 + j * 4]);
                    acc[j*4+0] += w[si] * vv.x;
                    acc[j*4+1] += w[si] * vv.y;
                    acc[j*4+2] += w[si] * vv.z;
                    acc[j*4+3] += w[si] * vv.w;
                }
            }
            m = nm;
        }
    }

    const float inv_l = 1.f / l;
    #pragma unroll
    for (int j = 0; j < 4; ++j) {
        float4 vv = make_float4(acc[j*4+0] * inv_l, acc[j*4+1] * inv_l,
                                acc[j*4+2] * inv_l, acc[j*4+3] * inv_l);
        *reinterpret_cast<float4*>(
            &out[base + (size_t)qrow * HH + hg * 16 + j * 4]) = vv;
    }
}

// ---------------------------------------------------------------------------
extern "C" void kernel_launch(void* const* d_in, const int* in_sizes, int n_in,
                              void* d_out, int out_size, void* d_ws, size_t ws_size,
                              hipStream_t stream)
{
    const float* x  = (const float*)d_in[0];
    const float* Wk = (const float*)d_in[1];
    const float* Wq = (const float*)d_in[2];
    const float* Wv = (const float*)d_in[3];
    float* out = (float*)d_out;

    const size_t MH = (size_t)BB * TT * HH;   // 8.4M elements
    float* kbuf = (float*)d_ws;               // needs 3*MH*4 = 100.7 MB of ws
    float* qbuf = kbuf + MH;
    float* vbuf = qbuf + MH;

    dim3 g1(BB * TT / 128, 3);
    qkv_gemm<<<g1, 256, 0, stream>>>(x, Wk, Wq, Wv, kbuf, qbuf, vbuf);

    dim3 g2(4, BB);
    attn<<<g2, 256, 0, stream>>>(qbuf, kbuf, vbuf, out);
}

// Round 2
// 459.674 us; speedup vs baseline: 1.4012x; 1.4012x over previous
//
#include <hip/hip_runtime.h>
#include <math.h>

#define BB 512
#define TT 256
#define CC 384
#define HH 64

typedef __attribute__((ext_vector_type(4))) float f32x4;
typedef __attribute__((ext_vector_type(8))) short bf16x8;
typedef __attribute__((ext_vector_type(4))) unsigned short ushort4v;

#define MFMA16(a, b, c) __builtin_amdgcn_mfma_f32_16x16x32_bf16((a), (b), (c), 0, 0, 0)

__device__ __forceinline__ unsigned short f2bf(float f) {
    union { float f; unsigned u; } v; v.f = f;
    unsigned r = v.u + 0x7FFFu + ((v.u >> 16) & 1u);   // round-to-nearest-even
    return (unsigned short)(r >> 16);
}
__device__ __forceinline__ float bf2f(unsigned short b) {
    union { unsigned u; float f; } v; v.u = ((unsigned)b) << 16;
    return v.f;
}

// ---------------------------------------------------------------------------
// Pre-kernel: W [C][H] fp32 -> Wt [mat][split(hi,lo)][H][C] bf16
// ---------------------------------------------------------------------------
__global__ __launch_bounds__(256) void wt_kernel(
    const float* __restrict__ Wk, const float* __restrict__ Wq,
    const float* __restrict__ Wv, unsigned short* __restrict__ wt)
{
    int idx = blockIdx.x * 256 + threadIdx.x;          // 0 .. 3*384*64-1
    int mat = idx / (CC * HH);
    int rem = idx % (CC * HH);
    int c = rem / HH;                                  // coalesced over h
    int h = rem % HH;
    const float* W = (mat == 0) ? Wk : (mat == 1) ? Wq : Wv;
    float xv = W[c * HH + h];
    unsigned short hi = f2bf(xv);
    unsigned short lo = f2bf(xv - bf2f(hi));
    wt[((size_t)(mat * 2 + 0) * HH + h) * CC + c] = hi;
    wt[((size_t)(mat * 2 + 1) * HH + h) * CC + c] = lo;
}

// ---------------------------------------------------------------------------
// Kernel 1: QKV projection via bf16 MFMA with 3-product hi/lo split.
// No LDS: A-frags (x rows) loaded+converted from global; B-frags from Wt (L2-hot).
// mats 0,1 (k,q): swapped mfma(W,x) -> C[h][token] -> packed row-major stores.
// mat 2 (v):      mfma(x,W) -> C[token][h] -> packed v^T stores.
// Each wave: 32 rows x 64 h x 3 mats; acc = 96 VGPR.
// ---------------------------------------------------------------------------
__global__ __launch_bounds__(256) void qkv_gemm(
    const float* __restrict__ x,
    const unsigned short* __restrict__ wt,
    unsigned short* __restrict__ khp, unsigned short* __restrict__ klp,
    unsigned short* __restrict__ qhp,
    unsigned short* __restrict__ vthp, unsigned short* __restrict__ vtlp)
{
    const int tid = threadIdx.x;
    const int l = tid & 63, w = tid >> 6;
    const int lane16 = l & 15, g = l >> 4;
    const int rowbase = blockIdx.x * 128 + w * 32;

    f32x4 acc[3][4][2];
    #pragma unroll
    for (int m = 0; m < 3; ++m)
        #pragma unroll
        for (int h = 0; h < 4; ++h)
            #pragma unroll
            for (int t = 0; t < 2; ++t)
                acc[m][h][t] = (f32x4){0.f, 0.f, 0.f, 0.f};

    const float* xr0 = x + (size_t)(rowbase + lane16) * CC;
    const float* xr1 = xr0 + (size_t)16 * CC;

    for (int k0 = 0; k0 < CC; k0 += 32) {
        bf16x8 xh[2], xl[2];
        #pragma unroll
        for (int tt = 0; tt < 2; ++tt) {
            const float* p = (tt == 0 ? xr0 : xr1) + k0 + g * 8;
            f32x4 a = *(const f32x4*)(p);
            f32x4 b2 = *(const f32x4*)(p + 4);
            #pragma unroll
            for (int j = 0; j < 4; ++j) {
                unsigned short hi = f2bf(a[j]);
                xh[tt][j] = (short)hi;
                xl[tt][j] = (short)f2bf(a[j] - bf2f(hi));
            }
            #pragma unroll
            for (int j = 0; j < 4; ++j) {
                unsigned short hi = f2bf(b2[j]);
                xh[tt][4 + j] = (short)hi;
                xl[tt][4 + j] = (short)f2bf(b2[j] - bf2f(hi));
            }
        }
        #pragma unroll
        for (int mat = 0; mat < 3; ++mat) {
            #pragma unroll
            for (int ht = 0; ht < 4; ++ht) {
                const unsigned short* wb =
                    wt + ((size_t)(mat * 2) * HH + ht * 16 + lane16) * CC + k0 + g * 8;
                bf16x8 whi = *(const bf16x8*)wb;
                bf16x8 wlo = *(const bf16x8*)(wb + (size_t)HH * CC);
                #pragma unroll
                for (int tt = 0; tt < 2; ++tt) {
                    if (mat < 2) {
                        acc[mat][ht][tt] = MFMA16(whi, xh[tt], acc[mat][ht][tt]);
                        acc[mat][ht][tt] = MFMA16(whi, xl[tt], acc[mat][ht][tt]);
                        acc[mat][ht][tt] = MFMA16(wlo, xh[tt], acc[mat][ht][tt]);
                    } else {
                        acc[mat][ht][tt] = MFMA16(xh[tt], whi, acc[mat][ht][tt]);
                        acc[mat][ht][tt] = MFMA16(xl[tt], whi, acc[mat][ht][tt]);
                        acc[mat][ht][tt] = MFMA16(xh[tt], wlo, acc[mat][ht][tt]);
                    }
                }
            }
        }
    }

    const int bidx = blockIdx.x >> 1;
    const int tpart = (blockIdx.x & 1) * 128;
    #pragma unroll
    for (int ht = 0; ht < 4; ++ht) {
        #pragma unroll
        for (int tt = 0; tt < 2; ++tt) {
            // k: hi+lo planes, row-major [b*T+t][H]
            {
                f32x4 a = acc[0][ht][tt];
                ushort4v hi, lo;
                #pragma unroll
                for (int r = 0; r < 4; ++r) {
                    hi[r] = f2bf(a[r]);
                    lo[r] = f2bf(a[r] - bf2f(hi[r]));
                }
                size_t tok = (size_t)rowbase + tt * 16 + lane16;
                size_t off = tok * HH + ht * 16 + g * 4;
                *(ushort4v*)&khp[off] = hi;
                *(ushort4v*)&klp[off] = lo;
            }
            // q: hi only
            {
                f32x4 a = acc[1][ht][tt];
                ushort4v hi;
                #pragma unroll
                for (int r = 0; r < 4; ++r) hi[r] = f2bf(a[r]);
                size_t tok = (size_t)rowbase + tt * 16 + lane16;
                *(ushort4v*)&qhp[tok * HH + ht * 16 + g * 4] = hi;
            }
            // v: hi+lo transposed planes [b][h][t]
            {
                f32x4 a = acc[2][ht][tt];
                ushort4v hi, lo;
                #pragma unroll
                for (int r = 0; r < 4; ++r) {
                    hi[r] = f2bf(a[r]);
                    lo[r] = f2bf(a[r] - bf2f(hi[r]));
                }
                int h = ht * 16 + lane16;
                int tloc = tpart + w * 32 + tt * 16 + g * 4;
                size_t voff = ((size_t)bidx * HH + h) * TT + tloc;
                *(ushort4v*)&vthp[voff] = hi;
                *(ushort4v*)&vtlp[voff] = lo;
            }
        }
    }
}

// ---------------------------------------------------------------------------
// Kernel 2: causal flash attention, bf16 MFMA.
// Swapped QK^T (S^T = K.Q^T) and OUT^T = V^T.P^T: softmax state lives at
// col=lane&15 for both, so zero cross-layout shuffles. 72-padded LDS rows
// (stride 144B -> 2-way bank aliasing = free). Wave w owns 16 q rows.
// ---------------------------------------------------------------------------
__global__ __launch_bounds__(256) void attn(
    const unsigned short* __restrict__ qhp,
    const unsigned short* __restrict__ khp, const unsigned short* __restrict__ klp,
    const unsigned short* __restrict__ vthp, const unsigned short* __restrict__ vtlp,
    float* __restrict__ out)
{
    __shared__ unsigned short Kh[64][72], Kl[64][72], Vh[64][72], Vl[64][72];
    __shared__ unsigned short Pl[4][16][72];

    const int tid = threadIdx.x;
    const int l = tid & 63, w = tid >> 6;
    const int lane16 = l & 15, g = l >> 4;
    const int qt = blockIdx.x, b = blockIdx.y;
    const int q_local = qt * 64 + w * 16 + lane16;    // token index of this lane's q
    const float scale = 0.05103103630798287f;         // 1/sqrt(384)

    const unsigned short* qrow = qhp + ((size_t)b * TT + q_local) * HH;
    bf16x8 qf0 = *(const bf16x8*)(qrow + g * 8);
    bf16x8 qf1 = *(const bf16x8*)(qrow + 32 + g * 8);

    f32x4 acc[4];
    #pragma unroll
    for (int i = 0; i < 4; ++i) acc[i] = (f32x4){0.f, 0.f, 0.f, 0.f};
    float m = -INFINITY, lsum = 0.f;

    const unsigned short* kbh = khp + (size_t)b * TT * HH;
    const unsigned short* kbl = klp + (size_t)b * TT * HH;
    const unsigned short* vbh = vthp + (size_t)b * HH * TT;
    const unsigned short* vbl = vtlp + (size_t)b * HH * TT;

    for (int kb = 0; kb <= qt; ++kb) {
        __syncthreads();
        #pragma unroll
        for (int r = 0; r < 2; ++r) {
            int idx = tid + r * 256;
            int row = idx >> 3, seg = idx & 7;
            *(bf16x8*)&Kh[row][seg * 8] =
                *(const bf16x8*)&kbh[(size_t)(kb * 64 + row) * HH + seg * 8];
            *(bf16x8*)&Kl[row][seg * 8] =
                *(const bf16x8*)&kbl[(size_t)(kb * 64 + row) * HH + seg * 8];
            *(bf16x8*)&Vh[row][seg * 8] =
                *(const bf16x8*)&vbh[(size_t)row * TT + kb * 64 + seg * 8];
            *(bf16x8*)&Vl[row][seg * 8] =
                *(const bf16x8*)&vbl[(size_t)row * TT + kb * 64 + seg * 8];
        }
        __syncthreads();

        // S^T = K.Q^T  (2 dim-chunks, products kh.qh + kl.qh)
        f32x4 s[4];
        #pragma unroll
        for (int kt = 0; kt < 4; ++kt) {
            f32x4 z = (f32x4){0.f, 0.f, 0.f, 0.f};
            bf16x8 ah0 = *(const bf16x8*)&Kh[kt * 16 + lane16][g * 8];
            bf16x8 ah1 = *(const bf16x8*)&Kh[kt * 16 + lane16][32 + g * 8];
            bf16x8 al0 = *(const bf16x8*)&Kl[kt * 16 + lane16][g * 8];
            bf16x8 al1 = *(const bf16x8*)&Kl[kt * 16 + lane16][32 + g * 8];
            z = MFMA16(ah0, qf0, z);
            z = MFMA16(ah1, qf1, z);
            z = MFMA16(al0, qf0, z);
            z = MFMA16(al1, qf1, z);
            s[kt] = z;
        }

        // online softmax over 64 keys (16 regs + shfl_xor 16,32)
        float sv[16];
        float mx = -INFINITY;
        #pragma unroll
        for (int kt = 0; kt < 4; ++kt) {
            #pragma unroll
            for (int r = 0; r < 4; ++r) {
                int key = kb * 64 + kt * 16 + g * 4 + r;
                float vvv = s[kt][r] * scale;
                vvv = (key <= q_local) ? vvv : -INFINITY;
                sv[kt * 4 + r] = vvv;
                mx = fmaxf(mx, vvv);
            }
        }
        mx = fmaxf(mx, __shfl_xor(mx, 16));
        mx = fmaxf(mx, __shfl_xor(mx, 32));
        float mnew = fmaxf(m, mx);
        float corr = __expf(m - mnew);
        float psum = 0.f;
        #pragma unroll
        for (int i = 0; i < 16; ++i) {
            float p = __expf(sv[i] - mnew);
            sv[i] = p;
            psum += p;
        }
        psum += __shfl_xor(psum, 16);
        psum += __shfl_xor(psum, 32);
        lsum = lsum * corr + psum;
        #pragma unroll
        for (int ht = 0; ht < 4; ++ht) acc[ht] = acc[ht] * corr;
        m = mnew;

        // P -> bf16 -> per-wave LDS row [q][key] (packed 8B writes)
        #pragma unroll
        for (int kt = 0; kt < 4; ++kt) {
            ushort4v pk;
            #pragma unroll
            for (int r = 0; r < 4; ++r) pk[r] = f2bf(sv[kt * 4 + r]);
            *(ushort4v*)&Pl[w][lane16][kt * 16 + g * 4] = pk;
        }

        // OUT^T += V^T.P^T  (V hi/lo x 2 key-chunks)
        bf16x8 pb0 = *(const bf16x8*)&Pl[w][lane16][g * 8];
        bf16x8 pb1 = *(const bf16x8*)&Pl[w][lane16][32 + g * 8];
        #pragma unroll
        for (int ht = 0; ht < 4; ++ht) {
            bf16x8 vh0 = *(const bf16x8*)&Vh[ht * 16 + lane16][g * 8];
            bf16x8 vh1 = *(const bf16x8*)&Vh[ht * 16 + lane16][32 + g * 8];
            bf16x8 vl0 = *(const bf16x8*)&Vl[ht * 16 + lane16][g * 8];
            bf16x8 vl1 = *(const bf16x8*)&Vl[ht * 16 + lane16][32 + g * 8];
            f32x4 a = acc[ht];
            a = MFMA16(vh0, pb0, a);
            a = MFMA16(vh1, pb1, a);
            a = MFMA16(vl0, pb0, a);
            a = MFMA16(vl1, pb1, a);
            acc[ht] = a;
        }
    }

    const float inv = 1.f / lsum;
    #pragma unroll
    for (int ht = 0; ht < 4; ++ht) {
        f32x4 o = acc[ht] * inv;
        *(f32x4*)&out[((size_t)b * TT + q_local) * HH + ht * 16 + g * 4] = o;
    }
}

// ---------------------------------------------------------------------------
// ws layout (bf16 elems):  Wt 3*2*64*384 = 147456
//   then 5 planes of B*T*H = 8388608 each: kh, kl, qh, vTh, vTl
// total = 84.2 MB  (< the 100.7 MB proven available in round 0)
// ---------------------------------------------------------------------------
extern "C" void kernel_launch(void* const* d_in, const int* in_sizes, int n_in,
                              void* d_out, int out_size, void* d_ws, size_t ws_size,
                              hipStream_t stream)
{
    const float* x  = (const float*)d_in[0];
    const float* Wk = (const float*)d_in[1];
    const float* Wq = (const float*)d_in[2];
    const float* Wv = (const float*)d_in[3];
    float* out = (float*)d_out;

    unsigned short* wsp = (unsigned short*)d_ws;
    const size_t PLANE = (size_t)BB * TT * HH;
    unsigned short* wt   = wsp;
    unsigned short* khp  = wsp + 147456;
    unsigned short* klp  = khp + PLANE;
    unsigned short* qhp  = klp + PLANE;
    unsigned short* vthp = qhp + PLANE;
    unsigned short* vtlp = vthp + PLANE;

    wt_kernel<<<dim3(288), 256, 0, stream>>>(Wk, Wq, Wv, wt);
    qkv_gemm<<<dim3(BB * TT / 128), 256, 0, stream>>>(x, wt, khp, klp, qhp, vthp, vtlp);
    attn<<<dim3(4, BB), 256, 0, stream>>>(qhp, khp, klp, vthp, vtlp, out);
}

// Round 3
// 337.695 us; speedup vs baseline: 1.9073x; 1.3612x over previous
//
#include <hip/hip_runtime.h>
#include <math.h>

#define BB 512
#define TT 256
#define CC 384
#define HH 64

typedef __attribute__((ext_vector_type(4))) float f32x4;
typedef __attribute__((ext_vector_type(8))) short bf16x8;
typedef __attribute__((ext_vector_type(4))) unsigned short ushort4v;

#define MFMA16(a, b, c) __builtin_amdgcn_mfma_f32_16x16x32_bf16((a), (b), (c), 0, 0, 0)

__device__ __forceinline__ unsigned short f2bf(float f) {
    union { float f; unsigned u; } v; v.f = f;
    unsigned r = v.u + 0x7FFFu + ((v.u >> 16) & 1u);   // RNE
    return (unsigned short)(r >> 16);
}
__device__ __forceinline__ float bf2f(unsigned short b) {
    union { unsigned u; float f; } v; v.u = ((unsigned)b) << 16;
    return v.f;
}

// ---------------------------------------------------------------------------
// Pre-kernel: W [C][H] fp32 -> wtg bf16(hi), layout [k0s 12][g 4][mat 3][h 64][j 8]
// where c = k0s*32 + g*8 + j. This layout == the per-K-step LDS image, so
// staging is a linear 12KB copy and ds_read_b128 frags are 2-way-conflict-free.
// ---------------------------------------------------------------------------
__global__ __launch_bounds__(256) void wt_kernel(
    const float* __restrict__ Wk, const float* __restrict__ Wq,
    const float* __restrict__ Wv, unsigned short* __restrict__ wtg)
{
    int idx = blockIdx.x * 256 + threadIdx.x;          // 0 .. 3*384*64-1
    int mat = idx / (CC * HH);
    int rem = idx % (CC * HH);
    int c = rem / HH;
    int h = rem % HH;
    const float* W = (mat == 0) ? Wk : (mat == 1) ? Wq : Wv;
    float xv = W[c * HH + h];
    int k0s = c >> 5, g = (c >> 3) & 3, j = c & 7;
    wtg[(((size_t)(k0s * 4 + g) * 3 + mat) * 64 + h) * 8 + j] = f2bf(xv);
}

// ---------------------------------------------------------------------------
// Kernel 1: QKV projection. 4 waves x 32 tokens = 128 tokens/block, all 3 mats.
// Products: x_hi.W_hi + x_lo.W_hi (W_lo dropped). W slice double-buffered in
// LDS (12KB/step), T14 async split, 1 barrier/step. x prefetched to regs.
// k,q via swapped mfma(W,x) -> C[h][t]; v via mfma(x,W) -> C[t][h] -> v^T.
// ---------------------------------------------------------------------------
__global__ __launch_bounds__(256) void qkv_gemm(
    const float* __restrict__ x,
    const unsigned short* __restrict__ wtg,
    unsigned short* __restrict__ khp, unsigned short* __restrict__ qhp,
    unsigned short* __restrict__ qlp, unsigned short* __restrict__ vthp)
{
    __shared__ unsigned short Wl[2][6144];             // 12KB per buffer

    const int tid = threadIdx.x;
    const int l = tid & 63, w = tid >> 6;
    const int lane16 = l & 15, g = l >> 4;
    const int rowbase = blockIdx.x * 128 + w * 32;

    f32x4 acc[3][4][2];
    #pragma unroll
    for (int m = 0; m < 3; ++m)
        #pragma unroll
        for (int h = 0; h < 4; ++h)
            #pragma unroll
            for (int t = 0; t < 2; ++t)
                acc[m][h][t] = (f32x4){0.f, 0.f, 0.f, 0.f};

    const float* xr0 = x + (size_t)(rowbase + lane16) * CC;
    const float* xr1 = xr0 + (size_t)16 * CC;

    // ---- prologue: stage W step 0, load x step 0
    bf16x8 wreg[3];
    #pragma unroll
    for (int i = 0; i < 3; ++i)
        wreg[i] = *(const bf16x8*)&wtg[(size_t)(tid + i * 256) * 8];
    f32x4 xn[2][2];
    #pragma unroll
    for (int tt = 0; tt < 2; ++tt) {
        const float* p = (tt == 0 ? xr0 : xr1) + g * 8;
        xn[tt][0] = *(const f32x4*)(p);
        xn[tt][1] = *(const f32x4*)(p + 4);
    }
    #pragma unroll
    for (int i = 0; i < 3; ++i)
        *(bf16x8*)&Wl[0][(tid + i * 256) * 8] = wreg[i];
    __syncthreads();

    for (int s = 0; s < 12; ++s) {
        const int cur = s & 1;
        // ---- issue next-step global loads early (latency hides under MFMA)
        f32x4 xn2[2][2];
        if (s < 11) {
            #pragma unroll
            for (int i = 0; i < 3; ++i)
                wreg[i] = *(const bf16x8*)&wtg[(size_t)(s + 1) * 6144
                                              + (size_t)(tid + i * 256) * 8];
            #pragma unroll
            for (int tt = 0; tt < 2; ++tt) {
                const float* p = (tt == 0 ? xr0 : xr1) + (s + 1) * 32 + g * 8;
                xn2[tt][0] = *(const f32x4*)(p);
                xn2[tt][1] = *(const f32x4*)(p + 4);
            }
        }
        // ---- convert current x to hi/lo bf16 frags
        bf16x8 xh[2], xl[2];
        #pragma unroll
        for (int tt = 0; tt < 2; ++tt) {
            #pragma unroll
            for (int j = 0; j < 4; ++j) {
                float v0 = xn[tt][0][j], v1 = xn[tt][1][j];
                unsigned short h0 = f2bf(v0), h1 = f2bf(v1);
                xh[tt][j]     = (short)h0;
                xh[tt][4 + j] = (short)h1;
                xl[tt][j]     = (short)f2bf(v0 - bf2f(h0));
                xl[tt][4 + j] = (short)f2bf(v1 - bf2f(h1));
            }
        }
        // ---- MFMA on current LDS buffer
        #pragma unroll
        for (int mat = 0; mat < 3; ++mat) {
            #pragma unroll
            for (int ht = 0; ht < 4; ++ht) {
                bf16x8 wf = *(const bf16x8*)
                    &Wl[cur][((g * 3 + mat) * 64 + ht * 16 + lane16) * 8];
                #pragma unroll
                for (int tt = 0; tt < 2; ++tt) {
                    if (mat < 2) {
                        acc[mat][ht][tt] = MFMA16(wf, xh[tt], acc[mat][ht][tt]);
                        acc[mat][ht][tt] = MFMA16(wf, xl[tt], acc[mat][ht][tt]);
                    } else {
                        acc[mat][ht][tt] = MFMA16(xh[tt], wf, acc[mat][ht][tt]);
                        acc[mat][ht][tt] = MFMA16(xl[tt], wf, acc[mat][ht][tt]);
                    }
                }
            }
        }
        // ---- write next W slice to other buffer; one barrier per step
        if (s < 11) {
            #pragma unroll
            for (int i = 0; i < 3; ++i)
                *(bf16x8*)&Wl[cur ^ 1][(tid + i * 256) * 8] = wreg[i];
            #pragma unroll
            for (int tt = 0; tt < 2; ++tt) {
                xn[tt][0] = xn2[tt][0];
                xn[tt][1] = xn2[tt][1];
            }
        }
        __syncthreads();
    }

    // ---- epilogue
    const int bidx = blockIdx.x >> 1;
    const int tpart = (blockIdx.x & 1) * 128;
    #pragma unroll
    for (int ht = 0; ht < 4; ++ht) {
        #pragma unroll
        for (int tt = 0; tt < 2; ++tt) {
            size_t tok = (size_t)rowbase + tt * 16 + lane16;
            // k: hi only
            {
                f32x4 a = acc[0][ht][tt];
                ushort4v hi;
                #pragma unroll
                for (int r = 0; r < 4; ++r) hi[r] = f2bf(a[r]);
                *(ushort4v*)&khp[tok * HH + ht * 16 + g * 4] = hi;
            }
            // q: hi + lo
            {
                f32x4 a = acc[1][ht][tt];
                ushort4v hi, lo;
                #pragma unroll
                for (int r = 0; r < 4; ++r) {
                    hi[r] = f2bf(a[r]);
                    lo[r] = f2bf(a[r] - bf2f(hi[r]));
                }
                size_t off = tok * HH + ht * 16 + g * 4;
                *(ushort4v*)&qhp[off] = hi;
                *(ushort4v*)&qlp[off] = lo;
            }
            // v: hi only, transposed [b][h][t]
            {
                f32x4 a = acc[2][ht][tt];
                ushort4v hi;
                #pragma unroll
                for (int r = 0; r < 4; ++r) hi[r] = f2bf(a[r]);
                int h = ht * 16 + lane16;
                int tloc = tpart + w * 32 + tt * 16 + g * 4;
                *(ushort4v*)&vthp[((size_t)bidx * HH + h) * TT + tloc] = hi;
            }
        }
    }
}

// ---------------------------------------------------------------------------
// Kernel 2: causal flash attention, bf16 MFMA, q in hi/lo registers.
// K/V double-buffered reg-staged LDS (46KB -> 3 blocks/CU), 1 barrier/tile,
// wave-level diagonal early-out, XCD-chunked block swizzle.
// ---------------------------------------------------------------------------
__global__ __launch_bounds__(256) void attn(
    const unsigned short* __restrict__ qhp, const unsigned short* __restrict__ qlp,
    const unsigned short* __restrict__ khp, const unsigned short* __restrict__ vthp,
    float* __restrict__ out)
{
    __shared__ unsigned short Kh[2][64][72];
    __shared__ unsigned short Vh[2][64][72];
    __shared__ unsigned short Pl[4][16][72];

    const int tid = threadIdx.x;
    const int l = tid & 63, w = tid >> 6;
    const int lane16 = l & 15, g = l >> 4;

    // XCD-chunked swizzle: consecutive remapped ids (same b) land on one XCD
    const int id = blockIdx.x;                 // 0..2047, 2048 % 8 == 0
    const int swz = (id & 7) * 256 + (id >> 3);
    const int b = swz >> 2, qt = swz & 3;

    const int q_local = qt * 64 + w * 16 + lane16;
    const float scale = 0.05103103630798287f;  // 1/sqrt(384)

    const unsigned short* qrow = qhp + ((size_t)b * TT + q_local) * HH;
    const unsigned short* qrl  = qlp + ((size_t)b * TT + q_local) * HH;
    bf16x8 qf0 = *(const bf16x8*)(qrow + g * 8);
    bf16x8 qf1 = *(const bf16x8*)(qrow + 32 + g * 8);
    bf16x8 ql0 = *(const bf16x8*)(qrl + g * 8);
    bf16x8 ql1 = *(const bf16x8*)(qrl + 32 + g * 8);

    f32x4 acc[4];
    #pragma unroll
    for (int i = 0; i < 4; ++i) acc[i] = (f32x4){0.f, 0.f, 0.f, 0.f};
    float m = -INFINITY, lsum = 0.f;

    const unsigned short* kbh = khp + (size_t)b * TT * HH;
    const unsigned short* vbh = vthp + (size_t)b * HH * TT;

    const int row0 = tid >> 3, seg0 = tid & 7;          // slot 0
    const int row1 = (tid + 256) >> 3, seg1 = tid & 7;  // slot 1

    // ---- prologue: stage tile 0
    bf16x8 kreg[2], vreg[2];
    kreg[0] = *(const bf16x8*)&kbh[(size_t)row0 * HH + seg0 * 8];
    kreg[1] = *(const bf16x8*)&kbh[(size_t)row1 * HH + seg1 * 8];
    vreg[0] = *(const bf16x8*)&vbh[(size_t)row0 * TT + seg0 * 8];
    vreg[1] = *(const bf16x8*)&vbh[(size_t)row1 * TT + seg1 * 8];
    *(bf16x8*)&Kh[0][row0][seg0 * 8] = kreg[0];
    *(bf16x8*)&Kh[0][row1][seg1 * 8] = kreg[1];
    *(bf16x8*)&Vh[0][row0][seg0 * 8] = vreg[0];
    *(bf16x8*)&Vh[0][row1][seg1 * 8] = vreg[1];
    __syncthreads();

    for (int kb = 0; kb <= qt; ++kb) {
        const int cur = kb & 1;
        // issue next-tile loads early
        if (kb < qt) {
            kreg[0] = *(const bf16x8*)&kbh[(size_t)((kb + 1) * 64 + row0) * HH + seg0 * 8];
            kreg[1] = *(const bf16x8*)&kbh[(size_t)((kb + 1) * 64 + row1) * HH + seg1 * 8];
            vreg[0] = *(const bf16x8*)&vbh[(size_t)row0 * TT + (kb + 1) * 64 + seg0 * 8];
            vreg[1] = *(const bf16x8*)&vbh[(size_t)row1 * TT + (kb + 1) * 64 + seg1 * 8];
        }

        // S^T = K.(Qhi^T) + K.(Qlo^T); diagonal tile: wave w needs kt <= w only
        const int ktmax = (kb == qt) ? w : 3;
        f32x4 s4[4];
        #pragma unroll
        for (int kt = 0; kt < 4; ++kt) {
            f32x4 z = (f32x4){0.f, 0.f, 0.f, 0.f};
            if (kt <= ktmax) {
                bf16x8 ah0 = *(const bf16x8*)&Kh[cur][kt * 16 + lane16][g * 8];
                bf16x8 ah1 = *(const bf16x8*)&Kh[cur][kt * 16 + lane16][32 + g * 8];
                z = MFMA16(ah0, qf0, z);
                z = MFMA16(ah1, qf1, z);
                z = MFMA16(ah0, ql0, z);
                z = MFMA16(ah1, ql1, z);
            }
            s4[kt] = z;
        }

        // online softmax (reduce over g via shfl 16,32)
        float sv[16];
        float mx = -INFINITY;
        #pragma unroll
        for (int kt = 0; kt < 4; ++kt) {
            #pragma unroll
            for (int r = 0; r < 4; ++r) {
                int key = kb * 64 + kt * 16 + g * 4 + r;
                float vvv = s4[kt][r] * scale;
                vvv = (kt <= ktmax && key <= q_local) ? vvv : -INFINITY;
                sv[kt * 4 + r] = vvv;
                mx = fmaxf(mx, vvv);
            }
        }
        mx = fmaxf(mx, __shfl_xor(mx, 16));
        mx = fmaxf(mx, __shfl_xor(mx, 32));
        float mnew = fmaxf(m, mx);
        float corr = __expf(m - mnew);
        float psum = 0.f;
        #pragma unroll
        for (int i = 0; i < 16; ++i) {
            float p = __expf(sv[i] - mnew);
            sv[i] = p;
            psum += p;
        }
        psum += __shfl_xor(psum, 16);
        psum += __shfl_xor(psum, 32);
        lsum = lsum * corr + psum;
        #pragma unroll
        for (int ht = 0; ht < 4; ++ht) acc[ht] = acc[ht] * corr;
        m = mnew;

        // P -> bf16 -> per-wave LDS
        #pragma unroll
        for (int kt = 0; kt < 4; ++kt) {
            ushort4v pk;
            #pragma unroll
            for (int r = 0; r < 4; ++r) pk[r] = f2bf(sv[kt * 4 + r]);
            *(ushort4v*)&Pl[w][lane16][kt * 16 + g * 4] = pk;
        }
        bf16x8 pb0 = *(const bf16x8*)&Pl[w][lane16][g * 8];
        bf16x8 pb1 = *(const bf16x8*)&Pl[w][lane16][32 + g * 8];

        // OUT^T += V^T.P^T
        #pragma unroll
        for (int ht = 0; ht < 4; ++ht) {
            bf16x8 vh0 = *(const bf16x8*)&Vh[cur][ht * 16 + lane16][g * 8];
            bf16x8 vh1 = *(const bf16x8*)&Vh[cur][ht * 16 + lane16][32 + g * 8];
            f32x4 a = acc[ht];
            a = MFMA16(vh0, pb0, a);
            a = MFMA16(vh1, pb1, a);
            acc[ht] = a;
        }

        // stage next tile into other buffer; one barrier per tile
        if (kb < qt) {
            *(bf16x8*)&Kh[cur ^ 1][row0][seg0 * 8] = kreg[0];
            *(bf16x8*)&Kh[cur ^ 1][row1][seg1 * 8] = kreg[1];
            *(bf16x8*)&Vh[cur ^ 1][row0][seg0 * 8] = vreg[0];
            *(bf16x8*)&Vh[cur ^ 1][row1][seg1 * 8] = vreg[1];
        }
        __syncthreads();
    }

    const float inv = 1.f / lsum;
    #pragma unroll
    for (int ht = 0; ht < 4; ++ht) {
        f32x4 o = acc[ht] * inv;
        *(f32x4*)&out[((size_t)b * TT + q_local) * HH + ht * 16 + g * 4] = o;
    }
}

// ---------------------------------------------------------------------------
// ws layout (bf16 elems): wtg 73728, then 4 planes of B*T*H = 8388608:
// khp, qhp, qlp, vthp. Total 67.3 MB.
// ---------------------------------------------------------------------------
extern "C" void kernel_launch(void* const* d_in, const int* in_sizes, int n_in,
                              void* d_out, int out_size, void* d_ws, size_t ws_size,
                              hipStream_t stream)
{
    const float* x  = (const float*)d_in[0];
    const float* Wk = (const float*)d_in[1];
    const float* Wq = (const float*)d_in[2];
    const float* Wv = (const float*)d_in[3];
    float* out = (float*)d_out;

    unsigned short* wsp = (unsigned short*)d_ws;
    const size_t PLANE = (size_t)BB * TT * HH;
    unsigned short* wtg  = wsp;
    unsigned short* khp  = wsp + 73728;
    unsigned short* qhp  = khp + PLANE;
    unsigned short* qlp  = qhp + PLANE;
    unsigned short* vthp = qlp + PLANE;

    wt_kernel<<<dim3(288), 256, 0, stream>>>(Wk, Wq, Wv, wtg);
    qkv_gemm<<<dim3(BB * TT / 128), 256, 0, stream>>>(x, wtg, khp, qhp, qlp, vthp);
    attn<<<dim3(2048), 256, 0, stream>>>(qhp, qlp, khp, vthp, out);
}